// Round 4
// baseline (187.112 us; speedup 1.0000x reference)
//
#include <hip/hip_runtime.h>
#include <math.h>

#define LQ 1024
#define BZ 8
#define D  512
#define NH 8
#define DH 64
#define IOU_THR 0.2f
#define COS_THR 0.2f
#define NEG (-1e30f)
#define FIXCAP 16384

typedef short bf16x8 __attribute__((ext_vector_type(8)));
typedef float f32x4  __attribute__((ext_vector_type(4)));

#define MFMA16(a, b, cacc) __builtin_amdgcn_mfma_f32_16x16x32_bf16(a, b, cacc, 0, 0, 0)

__device__ inline unsigned short f2bf(float x) {
    union { float f; unsigned int u; } v; v.f = x;
    unsigned int r = v.u + 0x7FFF + ((v.u >> 16) & 1);
    return (unsigned short)(r >> 16);
}

// Async global->LDS, 16B per lane. LDS dest must be wave-uniform base
// (HW scatters lane*16); global src is per-lane.
__device__ __forceinline__ void gload_lds16(const void* g, void* l) {
    __builtin_amdgcn_global_load_lds(
        (const __attribute__((address_space(1))) unsigned int*)g,
        (__attribute__((address_space(3))) unsigned int*)l, 16, 0, 0);
}

// ---------------------------------------------------------------------------
// Kernel 1: prep (query -> hi bf16, rnorm) + Wq/Wk/Wv -> bf16, fused.
// Also zeroes fix_cnt (replaces the separate hipMemsetAsync dispatch).
// ---------------------------------------------------------------------------
__global__ __launch_bounds__(256) void prep_kernel(const float* __restrict__ query,
                                                   const float* __restrict__ Wq,
                                                   const float* __restrict__ Wk,
                                                   const float* __restrict__ Wv,
                                                   unsigned short* __restrict__ hi,
                                                   unsigned short* __restrict__ Wb,
                                                   float* __restrict__ rnorm,
                                                   int* __restrict__ fix_cnt) {
    int blk = blockIdx.x, tid = threadIdx.x;
    if (blk < 2048) {
        int w = tid >> 6, lane = tid & 63;
        int row = blk * 4 + w;                  // = b*LQ + i
        int b = row >> 10, i = row & 1023;
        const float* src = query + ((size_t)i * BZ + b) * D + lane * 8;
        float4 v0 = *(const float4*)src;
        float4 v1 = *(const float4*)(src + 4);
        uint4 pk;
        pk.x = (unsigned)f2bf(v0.x) | ((unsigned)f2bf(v0.y) << 16);
        pk.y = (unsigned)f2bf(v0.z) | ((unsigned)f2bf(v0.w) << 16);
        pk.z = (unsigned)f2bf(v1.x) | ((unsigned)f2bf(v1.y) << 16);
        pk.w = (unsigned)f2bf(v1.z) | ((unsigned)f2bf(v1.w) << 16);
        *(uint4*)(hi + (size_t)row * D + lane * 8) = pk;
        float ss = v0.x * v0.x + v0.y * v0.y + v0.z * v0.z + v0.w * v0.w
                 + v1.x * v1.x + v1.y * v1.y + v1.z * v1.z + v1.w * v1.w;
        #pragma unroll
        for (int s = 1; s < 64; s <<= 1) ss += __shfl_xor(ss, s);
        if (lane == 0) rnorm[row] = 1.0f / fmaxf(sqrtf(ss), 1e-8f);
    } else {
        if (blk == 2048 && tid == 0) *fix_cnt = 0;
        int t = (blk - 2048) * 256 + tid;
        int mat = t >> 16;
        int off = (t & 65535) * 4;
        const float* src = (mat == 0) ? Wq : (mat == 1) ? Wk : Wv;
        float4 v = *(const float4*)(src + off);
        uint2 p;
        p.x = (unsigned)f2bf(v.x) | ((unsigned)f2bf(v.y) << 16);
        p.y = (unsigned)f2bf(v.z) | ((unsigned)f2bf(v.w) << 16);
        *(uint2*)(Wb + (size_t)mat * D * D + off) = p;
    }
}

// ---------------------------------------------------------------------------
// Kernel 2: fused QKV + symmetric mask GEMMs — FAT-WAVE version.
// Block tile 256x128, 4 waves, per-wave tile 128x64: 32 MFMA + 12 ds_read_b128
// per BK=32 step (2x the MFMA:overhead ratio of the old 64x64 wave tile).
// 3-buffer LDS rotation, ONE barrier per step, counted vmcnt(6): per step k
// {issue k+2's 6 loads into buf[(k+2)%3] -> ds_read 12 from buf[k%3] ->
// lgkmcnt(0) -> setprio(1) 32xMFMA setprio(0) -> vmcnt(6) -> s_barrier}.
// acc[8][4] = 128 VGPR; __launch_bounds__(256,2) caps VGPR at 256 ->
// 2 blocks/CU (LDS 72KB staging, epilogues alias it after the final barrier).
// Grid 544: 160 mask tiles first (20 per batch, jt>=2it over 256x128 tiles;
// every tile writes direct AND transposed — overlap writes are bitwise-
// identical by fp commutativity; ulp-borderline cells are in the fixup band),
// then 384 QKV tiles. Both halves keep blk%8 XCD pinning (160%8==384%8==0).
// ---------------------------------------------------------------------------
__global__ __launch_bounds__(256, 2) void gemm_kernel(const unsigned short* __restrict__ hi,
                                                      const unsigned short* __restrict__ Wb,
                                                      const float* __restrict__ rnorm,
                                                      const float* __restrict__ segments,
                                                      const float* __restrict__ bq,
                                                      const float* __restrict__ bk,
                                                      const float* __restrict__ bv,
                                                      unsigned char* __restrict__ mask,
                                                      unsigned char* __restrict__ summ,
                                                      int* __restrict__ fix_cnt,
                                                      unsigned int* __restrict__ fix_list,
                                                      unsigned short* __restrict__ Qb,
                                                      unsigned short* __restrict__ Kb,
                                                      unsigned short* __restrict__ Vt) {
    // SMEM union: staging A0|A1|A2 (3x16KB) + B0|B1|B2 (3x8KB) = 72KB.
    // QKV epilogue reuses as skewed 128x128 C half-tile (35KB);
    // mask epilogue reuses first 6KB as iSE(256)|jSE(128).
    __shared__ __align__(16) char SMEM[73728];
    __shared__ int summ_d[16][2], summ_t[8][4];

    int blk = blockIdx.x, tid = threadIdx.x, w = tid >> 6, lane = tid & 63;
    int c = lane & 15, q4 = lane >> 4;
    int wr2 = w >> 1, wc2 = w & 1;     // wave row-half (128 rows), col-half (64 cols)

    bool is_qkv = blk >= 160;
    const char *Asrc, *Bsrc;
    int b = 0, i0 = 0, j0 = 0, z = 0, m0 = 0, n0 = 0;
    if (is_qkv) {
        int x = blk - 160;
        int g = (x & 7) + 8 * ((x >> 3) / 12);   // m-group 0..31, XCD-pinned g%8
        int inner = (x >> 3) % 12;               // z*4 + n-quarter
        z = inner >> 2;
        m0 = g * 256;
        n0 = (inner & 3) * 128;
        Asrc = (const char*)(hi + (size_t)m0 * D);
        Bsrc = (const char*)(Wb + (size_t)z * D * D + (size_t)n0 * D);
    } else {
        b = blk & 7;                   // xcd = batch
        int t = blk >> 3;              // 0..19: (it,jt), it 256-row, jt 128-col, jt>=2it
        int it, jt;
        if (t < 8)       { it = 0; jt = t; }
        else if (t < 14) { it = 1; jt = 2 + (t - 8); }
        else if (t < 18) { it = 2; jt = 4 + (t - 14); }
        else             { it = 3; jt = 6 + (t - 18); }
        i0 = it * 256; j0 = jt * 128;
        Asrc = (const char*)(hi + ((size_t)b * LQ + i0) * D);
        Bsrc = (const char*)(hi + ((size_t)b * LQ + j0) * D);
        if (tid < 32) {
            summ_d[tid >> 1][tid & 1] = 0;
            summ_t[tid >> 2][tid & 3] = 0;
        }
    }

    // staging geometry (BK=32): chunk = 16 rows x 64B = 1KB. A: 16 chunks,
    // B: 8 chunks. Wave w stages A chunks 4w..4w+3, B chunks 2w..2w+1
    // (6 gload_lds16/wave/step). lane L -> row L>>2, phys slot L&3; source
    // pre-swizzled gl so slot s holds k-group s^((row>>1)&3). Read side:
    // k-group q4 at slot q4^((c>>1)&3).
    int lrow = lane >> 2;
    int gl   = (lane & 3) ^ ((lane >> 3) & 3);
    size_t goff = (size_t)lrow * 1024 + (size_t)gl * 16;

    char* const Abuf[3] = { SMEM, SMEM + 16384, SMEM + 32768 };
    char* const Bbuf[3] = { SMEM + 49152, SMEM + 57344, SMEM + 65536 };

#define STAGE_STEP(kb, Ad, Bd) do {                                            \
    _Pragma("unroll")                                                          \
    for (int m_ = 0; m_ < 4; m_++)                                             \
        gload_lds16(Asrc + (kb) + (size_t)(4 * w + m_) * 16384 + goff,         \
                    (Ad) + (4 * w + m_) * 1024);                               \
    _Pragma("unroll")                                                          \
    for (int m_ = 0; m_ < 2; m_++)                                             \
        gload_lds16(Bsrc + (kb) + (size_t)(2 * w + m_) * 16384 + goff,         \
                    (Bd) + (2 * w + m_) * 1024);                               \
} while (0)

    // prologue: k=0 -> buf0, k=1 -> buf1 (12 in flight), wait k=0 (vmcnt(6))
    STAGE_STEP((size_t)0, Abuf[0], Bbuf[0]);
    STAGE_STEP((size_t)64, Abuf[1], Bbuf[1]);
    asm volatile("s_waitcnt vmcnt(6)" ::: "memory");
    __builtin_amdgcn_s_barrier();

    f32x4 acc[8][4] = {};
    int rswz = (c >> 1) & 3;
    #pragma unroll
    for (int k = 0; k < 16; k++) {
        char* Ac = Abuf[k % 3];
        char* Bc = Bbuf[k % 3];
        // issue k+2 into buf[(k+2)%3] (last read at step k-1; protected by
        // that step's barrier)
        if (k < 14)
            STAGE_STEP((size_t)(k + 2) * 64, Abuf[(k + 2) % 3], Bbuf[(k + 2) % 3]);
        // ds_read this step's fragments: 8 A (wave's 128 rows) + 4 B (64 cols)
        bf16x8 af[8], bf[4];
        #pragma unroll
        for (int f = 0; f < 8; f++)
            af[f] = *(const bf16x8*)(Ac + ((wr2 * 128 + f * 16 + c) * 32 + (q4 ^ rswz) * 8) * 2);
        #pragma unroll
        for (int f = 0; f < 4; f++)
            bf[f] = *(const bf16x8*)(Bc + ((wc2 * 64 + f * 16 + c) * 32 + (q4 ^ rswz) * 8) * 2);
        asm volatile("s_waitcnt lgkmcnt(0)" ::: "memory");
        __builtin_amdgcn_sched_barrier(0);
        __builtin_amdgcn_s_setprio(1);
        #pragma unroll
        for (int fr = 0; fr < 8; fr++)
            #pragma unroll
            for (int fc = 0; fc < 4; fc++)
                acc[fr][fc] = MFMA16(af[fr], bf[fc], acc[fr][fc]);
        __builtin_amdgcn_s_setprio(0);
        if (k < 15) {
            if (k < 14) asm volatile("s_waitcnt vmcnt(6)" ::: "memory");
            else        asm volatile("s_waitcnt vmcnt(0)" ::: "memory");
            __builtin_amdgcn_s_barrier();
        }
    }
#undef STAGE_STEP
    // all waves' step-15 ds_reads done; SMEM safe to reuse after this barrier
    __builtin_amdgcn_s_barrier();

    if (is_qkv) {
        const float* bias = (z == 0) ? bq : (z == 1) ? bk : bv;
        // two 128-row halves through the skewed 128x128 C tile
        #pragma unroll
        for (int h = 0; h < 2; h++) {
            if (wr2 == h) {
                #pragma unroll
                for (int fr = 0; fr < 8; fr++)
                    #pragma unroll
                    for (int r = 0; r < 4; r++) {
                        int row = fr * 16 + q4 * 4 + r;     // 0..127
                        char* rbase = SMEM + row * 272 + (row >> 3) * 16;
                        #pragma unroll
                        for (int fc = 0; fc < 4; fc++) {
                            int col = wc2 * 64 + fc * 16 + c;
                            *(unsigned short*)(rbase + col * 2) =
                                f2bf(acc[fr][fc][r] + bias[n0 + col]);
                        }
                    }
            }
            __syncthreads();
            int rbase0 = m0 + h * 128;
            int bb = rbase0 >> 10, ib = rbase0 & 1023;
            if (z < 2) {
                unsigned short* dst = (z == 0) ? Qb : Kb;
                #pragma unroll
                for (int it2 = 0; it2 < 8; it2++) {
                    int idx = it2 * 256 + tid;
                    int row = idx >> 4, cg = idx & 15;
                    uint4 v = *(const uint4*)(SMEM + row * 272 + (row >> 3) * 16 + cg * 16);
                    int n = n0 + cg * 8;
                    int hh = n >> 6, dh = n & 63;
                    *(uint4*)(dst + (((size_t)bb * NH + hh) * LQ + ib + row) * DH + dh) = v;
                }
            } else {
                #pragma unroll
                for (int it2 = 0; it2 < 8; it2++) {
                    int idx = it2 * 256 + tid;
                    int rowg = idx & 15, colI = idx >> 4;
                    union { unsigned short s[8]; uint4 v; } u;
                    char* gbase = SMEM + rowg * 16;   // (row>>3)*16 with row=rowg*8+rr
                    #pragma unroll
                    for (int rr = 0; rr < 8; rr++)
                        u.s[rr] = *(const unsigned short*)(gbase + (rowg * 8 + rr) * 272 + colI * 2);
                    int n = n0 + colI;
                    int hh = n >> 6, dh = n & 63;
                    *(uint4*)(Vt + (((size_t)bb * NH + hh) * DH + dh) * LQ + ib + rowg * 8) = u.v;
                }
            }
            __syncthreads();
        }
    } else {
        // stage segment geometry + rnorm into SMEM-aliased iSE/jSE
        float4* iSE = (float4*)SMEM;            // 256 * 16B = 4KB
        float4* jSE = (float4*)(SMEM + 4096);   // 128 * 16B = 2KB
        const float2* seg2 = (const float2*)(segments + (size_t)b * LQ * 2);
        const float* rn = rnorm + b * LQ;
        {
            float2 cl = seg2[i0 + tid];
            iSE[tid] = make_float4(cl.x - cl.y * 0.5f, cl.x + cl.y * 0.5f, cl.y, rn[i0 + tid]);
            if (tid < 128) {
                float2 cl2 = seg2[j0 + tid];
                jSE[tid] = make_float4(cl2.x - cl2.y * 0.5f, cl2.x + cl2.y * 0.5f, cl2.y, rn[j0 + tid]);
            }
        }
        __syncthreads();

        unsigned char* mbase = mask + ((size_t)b << 20);
        #pragma unroll
        for (int fr = 0; fr < 8; fr++) {
            int anyun = 0;
            unsigned int tpack[4] = {0, 0, 0, 0};
            #pragma unroll
            for (int r = 0; r < 4; r++) {
                int il = wr2 * 128 + fr * 16 + q4 * 4 + r;
                int i = i0 + il;
                float4 I = iSE[il];
                #pragma unroll
                for (int fc = 0; fc < 4; fc++) {
                    int jl = wc2 * 64 + fc * 16 + c;
                    int j = j0 + jl;
                    float4 J = jSE[jl];
                    float cosv = acc[fr][fc][r] * I.w * J.w;
                    if (fabsf(cosv - COS_THR) < 1.5e-3f) {
                        int idx = atomicAdd(fix_cnt, 1);
                        if (idx < FIXCAP)
                            fix_list[idx] = ((unsigned int)b << 20) | ((unsigned int)i << 10) | j;
                    }
                    float inter = fmaxf(fminf(I.y, J.y) - fmaxf(I.x, J.x), 0.0f);
                    float uni   = I.z + J.z - inter;
                    float iou   = inter / uni;
                    bool adj = ((iou <= IOU_THR) || (i == j)) && (cosv > COS_THR);
                    mbase[(size_t)i * LQ + j] = adj ? 0 : 1;
                    tpack[fc] |= (adj ? 0u : 1u) << (8 * r);
                    anyun |= adj ? 1 : 0;
                }
            }
            if (anyun) atomicOr(&summ_d[wr2 * 8 + fr][wc2], 1);
            int ibase = i0 + wr2 * 128 + fr * 16 + q4 * 4;
            #pragma unroll
            for (int fc = 0; fc < 4; fc++) {
                int j = j0 + wc2 * 64 + fc * 16 + c;
                *(unsigned int*)&mbase[(size_t)j * LQ + ibase] = tpack[fc];
                if (tpack[fc] != 0x01010101u)
                    atomicOr(&summ_t[wc2 * 4 + fc][wr2 * 2 + (fr >> 2)], 1);
            }
        }
        __syncthreads();
        if (tid < 32) {
            int r = tid >> 1, cc = tid & 1;
            summ[((size_t)b * 64 + (i0 >> 4) + r) * 16 + (j0 >> 6) + cc] =
                summ_d[r][cc] ? 1 : 0;
        } else if (tid < 64) {
            int t2 = tid - 32;
            int r = t2 >> 2, cc = t2 & 3;
            summ[((size_t)b * 64 + (j0 >> 4) + r) * 16 + (i0 >> 6) + cc] =
                summ_t[r][cc] ? 1 : 0;
        }
    }
}

// ---------------------------------------------------------------------------
// Kernel 3: fixup — one wave per flagged element; cooperative fp64 dot over
// query rows. Patches BOTH (i,j) and (j,i). Stale summ=1 is safe.
// ---------------------------------------------------------------------------
__global__ __launch_bounds__(64) void fixup_kernel(const float* __restrict__ query,
                                                   const float* __restrict__ rnorm,
                                                   const float* __restrict__ segments,
                                                   const int* __restrict__ fix_cnt,
                                                   const unsigned int* __restrict__ fix_list,
                                                   unsigned char* __restrict__ mask,
                                                   unsigned char* __restrict__ summ) {
    int cnt = *fix_cnt; if (cnt > FIXCAP) cnt = FIXCAP;
    int lane = threadIdx.x;
    for (int e = blockIdx.x; e < cnt; e += gridDim.x) {
        unsigned int pk = fix_list[e];
        int b = pk >> 20, i = (pk >> 10) & 1023, j = pk & 1023;
        const float* hri = query + ((size_t)i * BZ + b) * D;
        const float* hrj = query + ((size_t)j * BZ + b) * D;
        double dd = 0.0;
        #pragma unroll
        for (int k = 0; k < D / 64; k++)
            dd += (double)hri[k * 64 + lane] * (double)hrj[k * 64 + lane];
        #pragma unroll
        for (int s = 1; s < 64; s <<= 1) dd += __shfl_xor(dd, s);
        if (lane == 0) {
            float rni = rnorm[b * LQ + i], rnj = rnorm[b * LQ + j];
            float cosv = (float)(dd * (double)rni * (double)rnj);
            const float* seg = segments + (size_t)b * LQ * 2;
            float ci = seg[i * 2], li = seg[i * 2 + 1];
            float cj = seg[j * 2], lj = seg[j * 2 + 1];
            float si = ci - li * 0.5f, ei = ci + li * 0.5f;
            float sj = cj - lj * 0.5f, ej = cj + lj * 0.5f;
            float inter = fmaxf(fminf(ei, ej) - fmaxf(si, sj), 0.0f);
            float iou = inter / (li + lj - inter);
            bool adj = ((iou <= IOU_THR) || (i == j)) && (cosv > COS_THR);
            unsigned char mv = adj ? 0 : 1;
            mask[((size_t)b * LQ + i) * LQ + j] = mv;
            mask[((size_t)b * LQ + j) * LQ + i] = mv;
            if (adj) {
                summ[((size_t)b * 64 + (i >> 4)) * 16 + (j >> 6)] = 1;
                summ[((size_t)b * 64 + (j >> 4)) * 16 + (i >> 6)] = 1;
            }
        }
    }
}

// ---------------------------------------------------------------------------
// Kernel 4: flash MFMA attention, summary-driven tile skipping; residual read
// directly from query (out[i][b][col] = O/l + query[i][b][col]).
// ---------------------------------------------------------------------------
__global__ __launch_bounds__(256) void attn_kernel(const unsigned short* __restrict__ Qb,
                                                   const unsigned short* __restrict__ Kb,
                                                   const unsigned short* __restrict__ Vt,
                                                   const unsigned char* __restrict__ mask,
                                                   const unsigned char* __restrict__ summ,
                                                   const float* __restrict__ query,
                                                   float* __restrict__ out) {
    int tid = threadIdx.x;
    int w = tid >> 6, lane = tid & 63;
    int c = lane & 15, q4 = lane >> 4;
    int hh = blockIdx.y, b = blockIdx.z;
    int i0 = blockIdx.x * 64 + w * 16;
    size_t bh = (size_t)b * NH + hh;

    __shared__ unsigned short p_lds[4][16][72];

    const unsigned short* Qrow = Qb + (bh * LQ + i0 + c) * DH;
    bf16x8 qa0 = *(const bf16x8*)(Qrow + q4 * 8);
    bf16x8 qa1 = *(const bf16x8*)(Qrow + 32 + q4 * 8);

    f32x4 O[4] = {};
    float m_r[4] = {NEG, NEG, NEG, NEG};
    float l_r[4] = {0.f, 0.f, 0.f, 0.f};

    const unsigned short* Kbase = Kb + bh * LQ * DH;
    const unsigned short* Vbase = Vt + bh * DH * LQ;
    const unsigned char*  mbase = mask + ((size_t)b * LQ + i0) * LQ;
    const unsigned char*  srow  = summ + ((size_t)b * 64 + (i0 >> 4)) * 16;

    for (int jt = 0; jt < 16; jt++) {
        if (!srow[jt]) continue;
        int j0 = jt * 64;
        f32x4 S[4] = {};
        #pragma unroll
        for (int cb = 0; cb < 4; cb++) {
            const unsigned short* krow = Kbase + (size_t)(j0 + cb * 16 + c) * DH;
            bf16x8 kf0 = *(const bf16x8*)(krow + q4 * 8);
            bf16x8 kf1 = *(const bf16x8*)(krow + 32 + q4 * 8);
            S[cb] = MFMA16(qa0, kf0, S[cb]);
            S[cb] = MFMA16(qa1, kf1, S[cb]);
        }
        float p[4][4];
        float tmax[4] = {NEG, NEG, NEG, NEG};
        #pragma unroll
        for (int cb = 0; cb < 4; cb++)
            #pragma unroll
            for (int r = 0; r < 4; r++) {
                float sc = S[cb][r] * 0.125f;
                unsigned char mm = mbase[(size_t)(q4 * 4 + r) * LQ + j0 + cb * 16 + c];
                sc = mm ? NEG : sc;
                p[cb][r] = sc;
                tmax[r] = fmaxf(tmax[r], sc);
            }
        #pragma unroll
        for (int r = 0; r < 4; r++) {
            float v = tmax[r];
            v = fmaxf(v, __shfl_xor(v, 1));
            v = fmaxf(v, __shfl_xor(v, 2));
            v = fmaxf(v, __shfl_xor(v, 4));
            v = fmaxf(v, __shfl_xor(v, 8));
            tmax[r] = v;
        }
        float rsum[4];
        #pragma unroll
        for (int r = 0; r < 4; r++) {
            float mn = fmaxf(m_r[r], tmax[r]);
            float alpha = __expf(m_r[r] - mn);
            m_r[r] = mn;
            l_r[r] *= alpha;
            #pragma unroll
            for (int cb2 = 0; cb2 < 4; cb2++) O[cb2][r] *= alpha;
            float s0 = 0.f;
            #pragma unroll
            for (int cb = 0; cb < 4; cb++) {
                float e = __expf(p[cb][r] - mn);
                p[cb][r] = e;
                s0 += e;
            }
            rsum[r] = s0;
        }
        #pragma unroll
        for (int r = 0; r < 4; r++) {
            float v = rsum[r];
            v += __shfl_xor(v, 1);
            v += __shfl_xor(v, 2);
            v += __shfl_xor(v, 4);
            v += __shfl_xor(v, 8);
            l_r[r] += v;
        }
        #pragma unroll
        for (int cb = 0; cb < 4; cb++)
            #pragma unroll
            for (int r = 0; r < 4; r++)
                p_lds[w][q4 * 4 + r][cb * 16 + c] = f2bf(p[cb][r]);
        #pragma unroll
        for (int s = 0; s < 2; s++) {
            bf16x8 pf = *(const bf16x8*)&p_lds[w][c][s * 32 + q4 * 8];
            #pragma unroll
            for (int cb = 0; cb < 4; cb++) {
                bf16x8 vf = *(const bf16x8*)(Vbase + (size_t)(cb * 16 + c) * LQ + j0 + s * 32 + q4 * 8);
                O[cb] = MFMA16(pf, vf, O[cb]);
            }
        }
    }
    #pragma unroll
    for (int r = 0; r < 4; r++) {
        int i = i0 + q4 * 4 + r;
        float inv = 1.0f / l_r[r];
        #pragma unroll
        for (int cb = 0; cb < 4; cb++) {
            int col = hh * 64 + cb * 16 + c;
            size_t oidx = ((size_t)i * BZ + b) * D + col;
            out[oidx] = O[cb][r] * inv + query[oidx];
        }
    }
}

// ---------------------------------------------------------------------------
extern "C" void kernel_launch(void* const* d_in, const int* in_sizes, int n_in,
                              void* d_out, int out_size, void* d_ws, size_t ws_size,
                              hipStream_t stream) {
    const float* query    = (const float*)d_in[0];
    const float* segments = (const float*)d_in[1];
    const float* Wq = (const float*)d_in[2];
    const float* bq = (const float*)d_in[3];
    const float* Wk = (const float*)d_in[4];
    const float* bk = (const float*)d_in[5];
    const float* Wv = (const float*)d_in[6];
    const float* bv = (const float*)d_in[7];
    float* out = (float*)d_out;

    const size_t NTOK = (size_t)BZ * LQ;
    char* ws = (char*)d_ws;
    unsigned short* hbuf  = (unsigned short*)ws;   ws += NTOK * D * 2;          // 8 MB
    unsigned short* Qb    = (unsigned short*)ws;   ws += NTOK * D * 2;          // 8 MB
    unsigned short* Kb    = (unsigned short*)ws;   ws += NTOK * D * 2;          // 8 MB
    unsigned short* Vt    = (unsigned short*)ws;   ws += NTOK * D * 2;          // 8 MB
    unsigned short* Wb    = (unsigned short*)ws;   ws += (size_t)3 * D * D * 2; // 1.5 MB
    float*          rnorm = (float*)ws;            ws += NTOK * 4;              // 32 KB
    unsigned char*  mask  = (unsigned char*)ws;    ws += (size_t)BZ * LQ * LQ;  // 8 MB
    unsigned char*  summ  = (unsigned char*)ws;    ws += 8192;                  // 8 KB
    int*            fix_cnt = (int*)ws;            ws += 64;
    unsigned int*   fix_list = (unsigned int*)ws;  /* 64 KB */

    prep_kernel<<<2816, 256, 0, stream>>>(query, Wq, Wk, Wv, hbuf, Wb, rnorm, fix_cnt);
    gemm_kernel<<<544, 256, 0, stream>>>(hbuf, Wb, rnorm, segments, bq, bk, bv,
                                         mask, summ, fix_cnt, fix_list, Qb, Kb, Vt);
    fixup_kernel<<<64, 64, 0, stream>>>(query, rnorm, segments, fix_cnt, fix_list, mask, summ);
    attn_kernel<<<dim3(LQ / 64, NH, BZ), 256, 0, stream>>>(Qb, Kb, Vt, mask, summ, query, out);
}

// Round 5
// 141.606 us; speedup vs baseline: 1.3214x; 1.3214x over previous
//
#include <hip/hip_runtime.h>
#include <math.h>

#define LQ 1024
#define BZ 8
#define D  512
#define NH 8
#define DH 64
#define IOU_THR 0.2f
#define COS_THR 0.2f
#define NEG (-1e30f)
#define FIXCAP 16384

typedef short bf16x8 __attribute__((ext_vector_type(8)));
typedef float f32x4  __attribute__((ext_vector_type(4)));

#define MFMA16(a, b, cacc) __builtin_amdgcn_mfma_f32_16x16x32_bf16(a, b, cacc, 0, 0, 0)

__device__ inline unsigned short f2bf(float x) {
    union { float f; unsigned int u; } v; v.f = x;
    unsigned int r = v.u + 0x7FFF + ((v.u >> 16) & 1);
    return (unsigned short)(r >> 16);
}

// Async global->LDS, 16B per lane. LDS dest must be wave-uniform base
// (HW scatters lane*16); global src is per-lane.
__device__ __forceinline__ void gload_lds16(const void* g, void* l) {
    __builtin_amdgcn_global_load_lds(
        (const __attribute__((address_space(1))) unsigned int*)g,
        (__attribute__((address_space(3))) unsigned int*)l, 16, 0, 0);
}

// ---------------------------------------------------------------------------
// Kernel 1: prep (query -> hi bf16, rnorm) + Wq/Wk/Wv -> bf16, fused.
// Also zeroes fix_cnt (replaces the separate hipMemsetAsync dispatch).
// ---------------------------------------------------------------------------
__global__ __launch_bounds__(256) void prep_kernel(const float* __restrict__ query,
                                                   const float* __restrict__ Wq,
                                                   const float* __restrict__ Wk,
                                                   const float* __restrict__ Wv,
                                                   unsigned short* __restrict__ hi,
                                                   unsigned short* __restrict__ Wb,
                                                   float* __restrict__ rnorm,
                                                   int* __restrict__ fix_cnt) {
    int blk = blockIdx.x, tid = threadIdx.x;
    if (blk < 2048) {
        int w = tid >> 6, lane = tid & 63;
        int row = blk * 4 + w;                  // = b*LQ + i
        int b = row >> 10, i = row & 1023;
        const float* src = query + ((size_t)i * BZ + b) * D + lane * 8;
        float4 v0 = *(const float4*)src;
        float4 v1 = *(const float4*)(src + 4);
        uint4 pk;
        pk.x = (unsigned)f2bf(v0.x) | ((unsigned)f2bf(v0.y) << 16);
        pk.y = (unsigned)f2bf(v0.z) | ((unsigned)f2bf(v0.w) << 16);
        pk.z = (unsigned)f2bf(v1.x) | ((unsigned)f2bf(v1.y) << 16);
        pk.w = (unsigned)f2bf(v1.z) | ((unsigned)f2bf(v1.w) << 16);
        *(uint4*)(hi + (size_t)row * D + lane * 8) = pk;
        float ss = v0.x * v0.x + v0.y * v0.y + v0.z * v0.z + v0.w * v0.w
                 + v1.x * v1.x + v1.y * v1.y + v1.z * v1.z + v1.w * v1.w;
        #pragma unroll
        for (int s = 1; s < 64; s <<= 1) ss += __shfl_xor(ss, s);
        if (lane == 0) rnorm[row] = 1.0f / fmaxf(sqrtf(ss), 1e-8f);
    } else {
        if (blk == 2048 && tid == 0) *fix_cnt = 0;
        int t = (blk - 2048) * 256 + tid;
        int mat = t >> 16;
        int off = (t & 65535) * 4;
        const float* src = (mat == 0) ? Wq : (mat == 1) ? Wk : Wv;
        float4 v = *(const float4*)(src + off);
        uint2 p;
        p.x = (unsigned)f2bf(v.x) | ((unsigned)f2bf(v.y) << 16);
        p.y = (unsigned)f2bf(v.z) | ((unsigned)f2bf(v.w) << 16);
        *(uint2*)(Wb + (size_t)mat * D * D + off) = p;
    }
}

// ---------------------------------------------------------------------------
// Kernel 2: fused QKV + symmetric mask GEMMs.
// K-loop: async global_load_lds staging, 2-deep in flight with counted
// vmcnt (T4): per step {ds_read k -> lgkmcnt(0) -> s_barrier -> issue k+2
// into the just-read buffer -> MFMA -> s_waitcnt vmcnt(4) -> s_barrier}.
// vmcnt(4) waits only k+1's 4 loads, leaving k+2's 4 in flight across the
// barrier -- never drains to 0 in the main loop. Each load gets ~2 K-steps
// of latency cover. Mask blocks (long epilogue) are ordered FIRST in the
// grid so their VALU-heavy epilogues overlap QKV blocks instead of forming
// the tail. 288 % 8 == 0 so blk%8 XCD pinning is unchanged for both halves.
// [R4 post-mortem: 128x64 fat-wave tile spills acc to scratch (VGPR cap) and
//  regresses 3.7x -- keep the spill-free 64x64 wave tile / 124 VGPR config.]
// ---------------------------------------------------------------------------
__global__ __launch_bounds__(256) void gemm_kernel(const unsigned short* __restrict__ hi,
                                                   const unsigned short* __restrict__ Wb,
                                                   const float* __restrict__ rnorm,
                                                   const float* __restrict__ segments,
                                                   const float* __restrict__ bq,
                                                   const float* __restrict__ bk,
                                                   const float* __restrict__ bv,
                                                   unsigned char* __restrict__ mask,
                                                   unsigned char* __restrict__ summ,
                                                   int* __restrict__ fix_cnt,
                                                   unsigned int* __restrict__ fix_list,
                                                   unsigned short* __restrict__ Qb,
                                                   unsigned short* __restrict__ Kb,
                                                   unsigned short* __restrict__ Vt) {
    // SMEM: K-loop ping-pong As0|As1|Bs0|Bs1 (4x8KB); epilogue reuses it as a
    // 128x128 C tile with skewed pitch: byte(row,col)=row*272+(row>>3)*16+col*2
    // (rows 16B-aligned, stride-8-row gathers bank-spread).
    __shared__ __align__(16) char SMEM[35072];
    __shared__ float4 iSE[128], jSE[128];
    __shared__ int summ_lds[8][2], summ_t_lds[8][2];
    short* const As0 = (short*)SMEM;
    short* const As1 = As0 + 4096;
    short* const Bs0 = As1 + 4096;
    short* const Bs1 = Bs0 + 4096;

    int blk = blockIdx.x, tid = threadIdx.x, w = tid >> 6, lane = tid & 63;
    int c = lane & 15, q4 = lane >> 4;
    int wr = w >> 1, wc = w & 1;

    bool is_qkv = blk >= 288;
    const char *Asrc, *Bsrc;
    int b = 0, i0 = 0, j0 = 0, z = 0, m0 = 0, n0 = 0;
    if (is_qkv) {
        // g = m-group 0..63 pinned to XCD g%8; inner = z*4 + n-quarter
        int x = blk - 288;
        int g = (x & 7) + 8 * ((x >> 3) / 12);
        int inner = (x >> 3) % 12;
        z = inner >> 2;
        m0 = g * 128;
        n0 = (inner & 3) * 128;
        Asrc = (const char*)(hi + (size_t)m0 * D);
        Bsrc = (const char*)(Wb + (size_t)z * D * D + (size_t)n0 * D);
    } else {
        int x = blk;                   // xcd = b = x%8
        b = x & 7;
        int t = x >> 3;                // 0..35 triangular index, it<=jt
        int it = 0;
        while (t >= 8 - it) { t -= 8 - it; it++; }
        int jt = it + t;
        i0 = it * 128; j0 = jt * 128;
        Asrc = (const char*)(hi + ((size_t)b * LQ + i0) * D);
        Bsrc = (const char*)(hi + ((size_t)b * LQ + j0) * D);
        if (tid < 16) {
            summ_lds[tid >> 1][tid & 1] = 0;
            summ_t_lds[tid >> 1][tid & 1] = 0;
        }
    }

    // staging geometry (BK=32): 8 chunks of 1KB (16 rows x 64B) per array.
    // wave w stages chunks 2w,2w+1 via global_load_lds: lane L lands at LDS
    // chunk_base + L*16 = row (L>>2), phys 16B slot L&3; source pre-swizzled
    // so slot L&3 holds logical k-group (L&3)^((L>>3)&3). Reads: q4^((c>>1)&3).
    int lrow = lane >> 2;
    int gl   = (lane & 3) ^ ((lane >> 3) & 3);
    size_t goff = (size_t)lrow * 1024 + (size_t)gl * 16;

    // prologue: issue k=0 -> buf0 and k=1 -> buf1 (8 loads in flight),
    // wait only k=0's 4 (vmcnt(4)), then barrier.
    #pragma unroll
    for (int m = 0; m < 2; m++) {
        int n = 2 * w + m;
        gload_lds16(Asrc + (size_t)n * 16384 + goff, (char*)As0 + n * 1024);
        gload_lds16(Bsrc + (size_t)n * 16384 + goff, (char*)Bs0 + n * 1024);
    }
    #pragma unroll
    for (int m = 0; m < 2; m++) {
        int n = 2 * w + m;
        gload_lds16(Asrc + 64 + (size_t)n * 16384 + goff, (char*)As1 + n * 1024);
        gload_lds16(Bsrc + 64 + (size_t)n * 16384 + goff, (char*)Bs1 + n * 1024);
    }
    asm volatile("s_waitcnt vmcnt(4)" ::: "memory");
    __builtin_amdgcn_s_barrier();

    f32x4 acc[4][4] = {};
    int rswz = (c >> 1) & 3;
    for (int k = 0; k < 16; k++) {
        short* Ac = (k & 1) ? As1 : As0;
        short* Bc = (k & 1) ? Bs1 : Bs0;
        // ds_read current K-step fragments
        bf16x8 af[4], bf[4];
        #pragma unroll
        for (int f = 0; f < 4; f++) {
            af[f] = *(const bf16x8*)&Ac[(wr * 64 + f * 16 + c) * 32 + (q4 ^ rswz) * 8];
            bf[f] = *(const bf16x8*)&Bc[(wc * 64 + f * 16 + c) * 32 + (q4 ^ rswz) * 8];
        }
        // all lanes' LDS reads complete before anyone overwrites this buffer
        asm volatile("s_waitcnt lgkmcnt(0)" ::: "memory");
        __builtin_amdgcn_sched_barrier(0);
        __builtin_amdgcn_s_barrier();
        // issue k+2 into the buffer we just finished reading
        if (k < 14) {
            size_t kb = (size_t)(k + 2) * 64;
            #pragma unroll
            for (int m = 0; m < 2; m++) {
                int n = 2 * w + m;
                gload_lds16(Asrc + kb + (size_t)n * 16384 + goff, (char*)Ac + n * 1024);
                gload_lds16(Bsrc + kb + (size_t)n * 16384 + goff, (char*)Bc + n * 1024);
            }
        }
        #pragma unroll
        for (int fr = 0; fr < 4; fr++)
            #pragma unroll
            for (int fc = 0; fc < 4; fc++)
                acc[fr][fc] = MFMA16(af[fr], bf[fc], acc[fr][fc]);
        if (k < 15) {
            // wait k+1's loads only; k+2's stay in flight across the barrier
            if (k < 14) asm volatile("s_waitcnt vmcnt(4)" ::: "memory");
            else        asm volatile("s_waitcnt vmcnt(0)" ::: "memory");
            __builtin_amdgcn_s_barrier();
        }
    }

    if (is_qkv) {
        const float* bias = (z == 0) ? bq : (z == 1) ? bk : bv;
        // stage C tile (bf16, +bias) into skewed LDS
        #pragma unroll
        for (int fr = 0; fr < 4; fr++)
            #pragma unroll
            for (int r = 0; r < 4; r++) {
                int row = wr * 64 + fr * 16 + q4 * 4 + r;
                char* rbase = SMEM + row * 272 + (row >> 3) * 16;
                #pragma unroll
                for (int fc = 0; fc < 4; fc++) {
                    int col = wc * 64 + fc * 16 + c;
                    *(unsigned short*)(rbase + col * 2) =
                        f2bf(acc[fr][fc][r] + bias[n0 + col]);
                }
            }
        __syncthreads();
        int bb = m0 >> 10, ib = m0 & 1023;
        if (z < 2) {
            unsigned short* dst = (z == 0) ? Qb : Kb;
            #pragma unroll
            for (int it2 = 0; it2 < 8; it2++) {
                int idx = it2 * 256 + tid;
                int row = idx >> 4, cg = idx & 15;
                uint4 v = *(const uint4*)(SMEM + row * 272 + (row >> 3) * 16 + cg * 16);
                int n = n0 + cg * 8;
                int hh = n >> 6, dh = n & 63;
                *(uint4*)(dst + (((size_t)bb * NH + hh) * LQ + ib + row) * DH + dh) = v;
            }
        } else {
            #pragma unroll
            for (int it2 = 0; it2 < 8; it2++) {
                int idx = it2 * 256 + tid;
                int rowg = idx & 15, colI = idx >> 4;
                union { unsigned short s[8]; uint4 v; } u;
                char* gbase = SMEM + rowg * 16;   // (row>>3)*16 with row=rowg*8+rr
                #pragma unroll
                for (int rr = 0; rr < 8; rr++)
                    u.s[rr] = *(const unsigned short*)(gbase + (rowg * 8 + rr) * 272 + colI * 2);
                int n = n0 + colI;
                int hh = n >> 6, dh = n & 63;
                *(uint4*)(Vt + (((size_t)bb * NH + hh) * DH + dh) * LQ + ib + rowg * 8) = u.v;
            }
        }
    } else {
        // stage segment geometry + rnorm (coalesced, once per block)
        const float2* seg2 = (const float2*)(segments + (size_t)b * LQ * 2);
        const float* rn = rnorm + b * LQ;
        if (tid < 128) {
            float2 cl = seg2[i0 + tid];
            iSE[tid] = make_float4(cl.x - cl.y * 0.5f, cl.x + cl.y * 0.5f, cl.y, rn[i0 + tid]);
        } else {
            float2 cl = seg2[j0 + tid - 128];
            jSE[tid - 128] = make_float4(cl.x - cl.y * 0.5f, cl.x + cl.y * 0.5f, cl.y, rn[j0 + tid - 128]);
        }
        __syncthreads();

        bool offdiag = (i0 != j0);
        unsigned char* mbase = mask + ((size_t)b << 20);
        int anyT[4] = {0, 0, 0, 0};
        #pragma unroll
        for (int fr = 0; fr < 4; fr++) {
            int anyun = 0;
            unsigned int tpack[4] = {0, 0, 0, 0};
            #pragma unroll
            for (int r = 0; r < 4; r++) {
                int il = wr * 64 + fr * 16 + q4 * 4 + r;
                int i = i0 + il;
                float4 I = iSE[il];
                #pragma unroll
                for (int fc = 0; fc < 4; fc++) {
                    int jl = wc * 64 + fc * 16 + c;
                    int j = j0 + jl;
                    float4 J = jSE[jl];
                    float cosv = acc[fr][fc][r] * I.w * J.w;
                    if (fabsf(cosv - COS_THR) < 1.5e-3f) {
                        int idx = atomicAdd(fix_cnt, 1);
                        if (idx < FIXCAP)
                            fix_list[idx] = ((unsigned int)b << 20) | ((unsigned int)i << 10) | j;
                    }
                    float inter = fmaxf(fminf(I.y, J.y) - fmaxf(I.x, J.x), 0.0f);
                    float uni   = I.z + J.z - inter;
                    float iou   = inter / uni;
                    bool adj = ((iou <= IOU_THR) || (i == j)) && (cosv > COS_THR);
                    mbase[(size_t)i * LQ + j] = adj ? 0 : 1;
                    tpack[fc] |= (adj ? 0u : 1u) << (8 * r);
                    anyun |= adj ? 1 : 0;
                    anyT[fc] |= adj ? 1 : 0;
                }
            }
            if (anyun) atomicOr(&summ_lds[wr * 4 + fr][wc], 1);
            if (offdiag) {
                int ibase = i0 + wr * 64 + fr * 16 + q4 * 4;
                #pragma unroll
                for (int fc = 0; fc < 4; fc++) {
                    int j = j0 + wc * 64 + fc * 16 + c;
                    *(unsigned int*)&mbase[(size_t)j * LQ + ibase] = tpack[fc];
                }
            }
        }
        if (offdiag) {
            #pragma unroll
            for (int fc = 0; fc < 4; fc++)
                if (anyT[fc]) atomicOr(&summ_t_lds[wc * 4 + fc][wr], 1);
        }
        __syncthreads();
        if (tid < 16) {
            int lit = tid >> 1, ljt = tid & 1;
            summ[((size_t)b * 64 + (i0 >> 4) + lit) * 16 + (j0 >> 6) + ljt] =
                summ_lds[lit][ljt] ? 1 : 0;
            if (offdiag)
                summ[((size_t)b * 64 + (j0 >> 4) + lit) * 16 + (i0 >> 6) + ljt] =
                    summ_t_lds[lit][ljt] ? 1 : 0;
        }
    }
}

// ---------------------------------------------------------------------------
// Kernel 3: fixup — one wave per flagged element; cooperative fp64 dot over
// query rows. Patches BOTH (i,j) and (j,i). Stale summ=1 is safe.
// ---------------------------------------------------------------------------
__global__ __launch_bounds__(64) void fixup_kernel(const float* __restrict__ query,
                                                   const float* __restrict__ rnorm,
                                                   const float* __restrict__ segments,
                                                   const int* __restrict__ fix_cnt,
                                                   const unsigned int* __restrict__ fix_list,
                                                   unsigned char* __restrict__ mask,
                                                   unsigned char* __restrict__ summ) {
    int cnt = *fix_cnt; if (cnt > FIXCAP) cnt = FIXCAP;
    int lane = threadIdx.x;
    for (int e = blockIdx.x; e < cnt; e += gridDim.x) {
        unsigned int pk = fix_list[e];
        int b = pk >> 20, i = (pk >> 10) & 1023, j = pk & 1023;
        const float* hri = query + ((size_t)i * BZ + b) * D;
        const float* hrj = query + ((size_t)j * BZ + b) * D;
        double dd = 0.0;
        #pragma unroll
        for (int k = 0; k < D / 64; k++)
            dd += (double)hri[k * 64 + lane] * (double)hrj[k * 64 + lane];
        #pragma unroll
        for (int s = 1; s < 64; s <<= 1) dd += __shfl_xor(dd, s);
        if (lane == 0) {
            float rni = rnorm[b * LQ + i], rnj = rnorm[b * LQ + j];
            float cosv = (float)(dd * (double)rni * (double)rnj);
            const float* seg = segments + (size_t)b * LQ * 2;
            float ci = seg[i * 2], li = seg[i * 2 + 1];
            float cj = seg[j * 2], lj = seg[j * 2 + 1];
            float si = ci - li * 0.5f, ei = ci + li * 0.5f;
            float sj = cj - lj * 0.5f, ej = cj + lj * 0.5f;
            float inter = fmaxf(fminf(ei, ej) - fmaxf(si, sj), 0.0f);
            float iou = inter / (li + lj - inter);
            bool adj = ((iou <= IOU_THR) || (i == j)) && (cosv > COS_THR);
            unsigned char mv = adj ? 0 : 1;
            mask[((size_t)b * LQ + i) * LQ + j] = mv;
            mask[((size_t)b * LQ + j) * LQ + i] = mv;
            if (adj) {
                summ[((size_t)b * 64 + (i >> 4)) * 16 + (j >> 6)] = 1;
                summ[((size_t)b * 64 + (j >> 4)) * 16 + (i >> 6)] = 1;
            }
        }
    }
}

// ---------------------------------------------------------------------------
// Kernel 4: flash MFMA attention, summary-driven tile skipping; residual read
// directly from query (out[i][b][col] = O/l + query[i][b][col]).
// ---------------------------------------------------------------------------
__global__ __launch_bounds__(256) void attn_kernel(const unsigned short* __restrict__ Qb,
                                                   const unsigned short* __restrict__ Kb,
                                                   const unsigned short* __restrict__ Vt,
                                                   const unsigned char* __restrict__ mask,
                                                   const unsigned char* __restrict__ summ,
                                                   const float* __restrict__ query,
                                                   float* __restrict__ out) {
    int tid = threadIdx.x;
    int w = tid >> 6, lane = tid & 63;
    int c = lane & 15, q4 = lane >> 4;
    int hh = blockIdx.y, b = blockIdx.z;
    int i0 = blockIdx.x * 64 + w * 16;
    size_t bh = (size_t)b * NH + hh;

    __shared__ unsigned short p_lds[4][16][72];

    const unsigned short* Qrow = Qb + (bh * LQ + i0 + c) * DH;
    bf16x8 qa0 = *(const bf16x8*)(Qrow + q4 * 8);
    bf16x8 qa1 = *(const bf16x8*)(Qrow + 32 + q4 * 8);

    f32x4 O[4] = {};
    float m_r[4] = {NEG, NEG, NEG, NEG};
    float l_r[4] = {0.f, 0.f, 0.f, 0.f};

    const unsigned short* Kbase = Kb + bh * LQ * DH;
    const unsigned short* Vbase = Vt + bh * DH * LQ;
    const unsigned char*  mbase = mask + ((size_t)b * LQ + i0) * LQ;
    const unsigned char*  srow  = summ + ((size_t)b * 64 + (i0 >> 4)) * 16;

    for (int jt = 0; jt < 16; jt++) {
        if (!srow[jt]) continue;
        int j0 = jt * 64;
        f32x4 S[4] = {};
        #pragma unroll
        for (int cb = 0; cb < 4; cb++) {
            const unsigned short* krow = Kbase + (size_t)(j0 + cb * 16 + c) * DH;
            bf16x8 kf0 = *(const bf16x8*)(krow + q4 * 8);
            bf16x8 kf1 = *(const bf16x8*)(krow + 32 + q4 * 8);
            S[cb] = MFMA16(qa0, kf0, S[cb]);
            S[cb] = MFMA16(qa1, kf1, S[cb]);
        }
        float p[4][4];
        float tmax[4] = {NEG, NEG, NEG, NEG};
        #pragma unroll
        for (int cb = 0; cb < 4; cb++)
            #pragma unroll
            for (int r = 0; r < 4; r++) {
                float sc = S[cb][r] * 0.125f;
                unsigned char mm = mbase[(size_t)(q4 * 4 + r) * LQ + j0 + cb * 16 + c];
                sc = mm ? NEG : sc;
                p[cb][r] = sc;
                tmax[r] = fmaxf(tmax[r], sc);
            }
        #pragma unroll
        for (int r = 0; r < 4; r++) {
            float v = tmax[r];
            v = fmaxf(v, __shfl_xor(v, 1));
            v = fmaxf(v, __shfl_xor(v, 2));
            v = fmaxf(v, __shfl_xor(v, 4));
            v = fmaxf(v, __shfl_xor(v, 8));
            tmax[r] = v;
        }
        float rsum[4];
        #pragma unroll
        for (int r = 0; r < 4; r++) {
            float mn = fmaxf(m_r[r], tmax[r]);
            float alpha = __expf(m_r[r] - mn);
            m_r[r] = mn;
            l_r[r] *= alpha;
            #pragma unroll
            for (int cb2 = 0; cb2 < 4; cb2++) O[cb2][r] *= alpha;
            float s0 = 0.f;
            #pragma unroll
            for (int cb = 0; cb < 4; cb++) {
                float e = __expf(p[cb][r] - mn);
                p[cb][r] = e;
                s0 += e;
            }
            rsum[r] = s0;
        }
        #pragma unroll
        for (int r = 0; r < 4; r++) {
            float v = rsum[r];
            v += __shfl_xor(v, 1);
            v += __shfl_xor(v, 2);
            v += __shfl_xor(v, 4);
            v += __shfl_xor(v, 8);
            l_r[r] += v;
        }
        #pragma unroll
        for (int cb = 0; cb < 4; cb++)
            #pragma unroll
            for (int r = 0; r < 4; r++)
                p_lds[w][q4 * 4 + r][cb * 16 + c] = f2bf(p[cb][r]);
        #pragma unroll
        for (int s = 0; s < 2; s++) {
            bf16x8 pf = *(const bf16x8*)&p_lds[w][c][s * 32 + q4 * 8];
            #pragma unroll
            for (int cb = 0; cb < 4; cb++) {
                bf16x8 vf = *(const bf16x8*)(Vbase + (size_t)(cb * 16 + c) * LQ + j0 + s * 32 + q4 * 8);
                O[cb] = MFMA16(pf, vf, O[cb]);
            }
        }
    }
    #pragma unroll
    for (int r = 0; r < 4; r++) {
        int i = i0 + q4 * 4 + r;
        float inv = 1.0f / l_r[r];
        #pragma unroll
        for (int cb = 0; cb < 4; cb++) {
            int col = hh * 64 + cb * 16 + c;
            size_t oidx = ((size_t)i * BZ + b) * D + col;
            out[oidx] = O[cb][r] * inv + query[oidx];
        }
    }
}

// ---------------------------------------------------------------------------
extern "C" void kernel_launch(void* const* d_in, const int* in_sizes, int n_in,
                              void* d_out, int out_size, void* d_ws, size_t ws_size,
                              hipStream_t stream) {
    const float* query    = (const float*)d_in[0];
    const float* segments = (const float*)d_in[1];
    const float* Wq = (const float*)d_in[2];
    const float* bq = (const float*)d_in[3];
    const float* Wk = (const float*)d_in[4];
    const float* bk = (const float*)d_in[5];
    const float* Wv = (const float*)d_in[6];
    const float* bv = (const float*)d_in[7];
    float* out = (float*)d_out;

    const size_t NTOK = (size_t)BZ * LQ;
    char* ws = (char*)d_ws;
    unsigned short* hbuf  = (unsigned short*)ws;   ws += NTOK * D * 2;          // 8 MB
    unsigned short* Qb    = (unsigned short*)ws;   ws += NTOK * D * 2;          // 8 MB
    unsigned short* Kb    = (unsigned short*)ws;   ws += NTOK * D * 2;          // 8 MB
    unsigned short* Vt    = (unsigned short*)ws;   ws += NTOK * D * 2;          // 8 MB
    unsigned short* Wb    = (unsigned short*)ws;   ws += (size_t)3 * D * D * 2; // 1.5 MB
    float*          rnorm = (float*)ws;            ws += NTOK * 4;              // 32 KB
    unsigned char*  mask  = (unsigned char*)ws;    ws += (size_t)BZ * LQ * LQ;  // 8 MB
    unsigned char*  summ  = (unsigned char*)ws;    ws += 8192;                  // 8 KB
    int*            fix_cnt = (int*)ws;            ws += 64;
    unsigned int*   fix_list = (unsigned int*)ws;  /* 64 KB */

    prep_kernel<<<2816, 256, 0, stream>>>(query, Wq, Wk, Wv, hbuf, Wb, rnorm, fix_cnt);
    gemm_kernel<<<1056, 256, 0, stream>>>(hbuf, Wb, rnorm, segments, bq, bk, bv,
                                          mask, summ, fix_cnt, fix_list, Qb, Kb, Vt);
    fixup_kernel<<<64, 64, 0, stream>>>(query, rnorm, segments, fix_cnt, fix_list, mask, summ);
    attn_kernel<<<dim3(LQ / 64, NH, BZ), 256, 0, stream>>>(Qb, Kb, Vt, mask, summ, query, out);
}